// Round 1
// baseline (1404.691 us; speedup 1.0000x reference)
//
#include <hip/hip_runtime.h>
#include <float.h>

// ---------------------------------------------------------------------------
// OnlineClustering: normalize -> GEMM (bf16 MFMA) -> Sinkhorn (factorized) ->
// assignments + CE loss.
//
// Factorization: sinkhorn normalizations are diagonal scalings, so
//   M_final[s,k] = M0[s,k] * C[b,k] * R[b,s],  M0 = exp((l - max_s l)/T + 50)
// Each iteration: t_k = sum_s M0*R ; C <- C/(C*t+eps) ; w_s = sum_k M0*C ;
//                 R <- R/(R*w+eps).
// ---------------------------------------------------------------------------

#define TT_INV 14.285714285714286f   // 1/0.07
#define TP_INV 8.333333333333334f    // 1/0.12
#define EXPMAX 50.0f
#define SK_EPS 1e-8f

typedef short v8s __attribute__((ext_vector_type(8)));
typedef float v4f __attribute__((ext_vector_type(4)));

__device__ inline unsigned short f2bf(float f){          // RNE float->bf16
  unsigned u = __float_as_uint(f);
  u += 0x7FFFu + ((u >> 16) & 1u);
  return (unsigned short)(u >> 16);
}
// order-preserving float<->uint for atomicMax on floats (incl. negatives)
__device__ inline unsigned encf(float f){
  unsigned u = __float_as_uint(f);
  return (u & 0x80000000u) ? ~u : (u | 0x80000000u);
}
__device__ inline float decf(unsigned e){
  unsigned u = (e & 0x80000000u) ? (e & 0x7FFFFFFFu) : ~e;
  return __uint_as_float(u);
}

// block = 256 threads (4 waves)
__device__ inline float blockReduceSum(float v, float* sb){
  #pragma unroll
  for(int o = 32; o; o >>= 1) v += __shfl_down(v, o);
  __syncthreads();
  if((threadIdx.x & 63) == 0) sb[threadIdx.x >> 6] = v;
  __syncthreads();
  return (sb[0] + sb[1]) + (sb[2] + sb[3]);
}
__device__ inline float blockReduceMax(float v, float* sb){
  #pragma unroll
  for(int o = 32; o; o >>= 1) v = fmaxf(v, __shfl_down(v, o));
  __syncthreads();
  if((threadIdx.x & 63) == 0) sb[threadIdx.x >> 6] = v;
  __syncthreads();
  return fmaxf(fmaxf(sb[0], sb[1]), fmaxf(sb[2], sb[3]));
}

__device__ inline void gl_lds16(const void* g, void* l){
  __builtin_amdgcn_global_load_lds(
      (const __attribute__((address_space(1))) void*)g,
      (__attribute__((address_space(3))) void*)l, 16, 0, 0);
}

// -------------------- init small buffers --------------------
__global__ __launch_bounds__(256) void init_k(unsigned* __restrict__ shiftenc,
                                              float* __restrict__ tbuf,
                                              float* __restrict__ Cb,
                                              float* __restrict__ Rb,
                                              float* __restrict__ lossacc){
  int i = blockIdx.x * 256 + threadIdx.x;   // grid covers 262144
  shiftenc[i] = 0u;       // encf(-inf) > 0, so 0 is below any real value
  tbuf[i] = 0.f;
  Cb[i] = 1.f;
  if(i < 8192) Rb[i] = 1.f;
  if(i == 0) lossacc[0] = 0.f;
}

// -------------------- normalize x rows, cast bf16 --------------------
__global__ __launch_bounds__(256) void norm_x_k(const float* __restrict__ x,
                                                unsigned short* __restrict__ xb){
  const int row = blockIdx.x, t = threadIdx.x;
  const float4 v = ((const float4*)(x + (size_t)row * 1024))[t];
  __shared__ float sb[4];
  float ss = v.x*v.x + v.y*v.y + v.z*v.z + v.w*v.w;
  float tot = blockReduceSum(ss, sb);
  float sc = 1.0f / fmaxf(sqrtf(tot), 1e-7f);
  ushort4 o = { f2bf(v.x*sc), f2bf(v.y*sc), f2bf(v.z*sc), f2bf(v.w*sc) };
  ((ushort4*)(xb + (size_t)row * 1024))[t] = o;
}

// -------------------- cast W bf16 --------------------
__global__ __launch_bounds__(256) void conv_w_k(const float* __restrict__ W,
                                                unsigned short* __restrict__ Wb){
  const size_t i = (size_t)blockIdx.x * 256 + threadIdx.x;
  const float4 v = ((const float4*)W)[i];
  ushort4 o = { f2bf(v.x), f2bf(v.y), f2bf(v.z), f2bf(v.w) };
  ((ushort4*)Wb)[i] = o;
}

// -------------------- bf16 GEMM (B^T form): C[m][n] = sum_d A[m][d]*B[n][d] --
// 128x128 block tile, BK=32, 4 waves each 64x64, global_load_lds width-16.
__global__ __launch_bounds__(256) void gemm_bt_k(const unsigned short* __restrict__ A,
                                                 const unsigned short* __restrict__ B,
                                                 float* __restrict__ C){
  __shared__ __align__(16) short As[128 * 32];
  __shared__ __align__(16) short Bs[128 * 32];
  const int t = threadIdx.x;
  const int L = t & 63, w = t >> 6;
  const int wm = w >> 1, wn = w & 1;
  const int quad = L >> 4, lr = L & 15;
  const int m0 = blockIdx.y * 128, n0 = blockIdx.x * 128;

  v4f acc[4][4];
  #pragma unroll
  for(int i = 0; i < 4; i++)
    #pragma unroll
    for(int j = 0; j < 4; j++) acc[i][j] = (v4f){0.f, 0.f, 0.f, 0.f};

  // staging chunks: 512 16B-chunks per tile, 2 per thread per tile
  const int c0 = t, c1 = t + 256;
  const int r0 = c0 >> 2, kc0 = c0 & 3;
  const int r1 = c1 >> 2, kc1 = c1 & 3;
  const unsigned short* gA0 = A + (size_t)(m0 + r0) * 1024 + kc0 * 8;
  const unsigned short* gA1 = A + (size_t)(m0 + r1) * 1024 + kc1 * 8;
  const unsigned short* gB0 = B + (size_t)(n0 + r0) * 1024 + kc0 * 8;
  const unsigned short* gB1 = B + (size_t)(n0 + r1) * 1024 + kc1 * 8;
  short* lA0 = &As[c0 * 8]; short* lA1 = &As[c1 * 8];
  short* lB0 = &Bs[c0 * 8]; short* lB1 = &Bs[c1 * 8];

  for(int kt = 0; kt < 32; ++kt){
    __syncthreads();
    const int ko = kt * 32;
    gl_lds16(gA0 + ko, lA0);
    gl_lds16(gA1 + ko, lA1);
    gl_lds16(gB0 + ko, lB0);
    gl_lds16(gB1 + ko, lB1);
    __syncthreads();
    v8s af[4], bf[4];
    #pragma unroll
    for(int mi = 0; mi < 4; mi++)
      af[mi] = *(const v8s*)&As[(wm*64 + mi*16 + lr) * 32 + quad * 8];
    #pragma unroll
    for(int ni = 0; ni < 4; ni++)
      bf[ni] = *(const v8s*)&Bs[(wn*64 + ni*16 + lr) * 32 + quad * 8];
    #pragma unroll
    for(int mi = 0; mi < 4; mi++)
      #pragma unroll
      for(int ni = 0; ni < 4; ni++)
        acc[mi][ni] = __builtin_amdgcn_mfma_f32_16x16x32_bf16(af[mi], bf[ni], acc[mi][ni], 0, 0, 0);
  }
  // C/D layout: col = lane&15, row = quad*4 + reg
  #pragma unroll
  for(int mi = 0; mi < 4; mi++){
    const int row = m0 + wm*64 + mi*16 + quad*4;
    #pragma unroll
    for(int ni = 0; ni < 4; ni++){
      const int col = n0 + wn*64 + ni*16 + lr;
      #pragma unroll
      for(int r = 0; r < 4; r++)
        C[(size_t)(row + r) * 8192 + col] = acc[mi][ni][r];
    }
  }
}

// -------------------- column max over S (per batch) --------------------
__global__ __launch_bounds__(256) void colmax_k(const float* __restrict__ logits,
                                                unsigned* __restrict__ shiftenc){
  const int kg = blockIdx.x, sg = blockIdx.y, b = blockIdx.z;
  const int col = kg * 1024 + threadIdx.x * 4;
  const float* base = logits + ((size_t)(b*256 + sg*8)) * 8192 + col;
  float4 m = { -FLT_MAX, -FLT_MAX, -FLT_MAX, -FLT_MAX };
  #pragma unroll
  for(int s = 0; s < 8; s++){
    float4 v = *(const float4*)(base + (size_t)s * 8192);
    m.x = fmaxf(m.x, v.x); m.y = fmaxf(m.y, v.y);
    m.z = fmaxf(m.z, v.z); m.w = fmaxf(m.w, v.w);
  }
  unsigned* p = shiftenc + (size_t)b * 8192 + col;
  atomicMax(p + 0, encf(m.x)); atomicMax(p + 1, encf(m.y));
  atomicMax(p + 2, encf(m.z)); atomicMax(p + 3, encf(m.w));
}

// -------------------- column sums t_k = sum_s M0*R --------------------
__global__ __launch_bounds__(256) void colsum_k(const float* __restrict__ logits,
                                                const unsigned* __restrict__ shiftenc,
                                                const float* __restrict__ Rb,
                                                float* __restrict__ tbuf){
  const int kg = blockIdx.x, sg = blockIdx.y, b = blockIdx.z;
  const int col = kg * 1024 + threadIdx.x * 4;
  const unsigned* sep = shiftenc + (size_t)b * 8192 + col;
  const float4 sh = { decf(sep[0]), decf(sep[1]), decf(sep[2]), decf(sep[3]) };
  const float* base = logits + ((size_t)(b*256 + sg*8)) * 8192 + col;
  const float* Rp = Rb + b*256 + sg*8;
  float4 acc = {0.f, 0.f, 0.f, 0.f};
  #pragma unroll
  for(int s = 0; s < 8; s++){
    const float rs = Rp[s];
    float4 v = *(const float4*)(base + (size_t)s * 8192);
    acc.x += __expf((v.x - sh.x)*TT_INV + EXPMAX) * rs;
    acc.y += __expf((v.y - sh.y)*TT_INV + EXPMAX) * rs;
    acc.z += __expf((v.z - sh.z)*TT_INV + EXPMAX) * rs;
    acc.w += __expf((v.w - sh.w)*TT_INV + EXPMAX) * rs;
  }
  float* tp = tbuf + (size_t)b * 8192 + col;
  atomicAdd(tp + 0, acc.x); atomicAdd(tp + 1, acc.y);
  atomicAdd(tp + 2, acc.z); atomicAdd(tp + 3, acc.w);
}

// -------------------- C update (and reset t for next iter) --------------------
__global__ __launch_bounds__(256) void updC_k(float* __restrict__ Cb,
                                              float* __restrict__ tbuf){
  const int i = blockIdx.x * 256 + threadIdx.x;
  const float c = Cb[i], tt = tbuf[i];
  Cb[i] = c / (c * tt + SK_EPS);
  tbuf[i] = 0.f;
}

// -------------------- row sums w_s = sum_k M0*C ; update R ----------------
__global__ __launch_bounds__(256) void rowsum_k(const float* __restrict__ logits,
                                                const unsigned* __restrict__ shiftenc,
                                                const float* __restrict__ Cb,
                                                float* __restrict__ Rb){
  const int row = blockIdx.x, t = threadIdx.x, b = row >> 8;
  const float* lrow = logits + (size_t)row * 8192;
  const unsigned* sep = shiftenc + (size_t)b * 8192;
  const float* Cp = Cb + (size_t)b * 8192;
  float acc = 0.f;
  #pragma unroll
  for(int it = 0; it < 8; ++it){
    const int k = it * 1024 + t * 4;
    float4 v = *(const float4*)(lrow + k);
    float4 sh = { decf(sep[k]), decf(sep[k+1]), decf(sep[k+2]), decf(sep[k+3]) };
    float4 c4 = *(const float4*)(Cp + k);
    acc += __expf((v.x - sh.x)*TT_INV + EXPMAX) * c4.x
         + __expf((v.y - sh.y)*TT_INV + EXPMAX) * c4.y
         + __expf((v.z - sh.z)*TT_INV + EXPMAX) * c4.z
         + __expf((v.w - sh.w)*TT_INV + EXPMAX) * c4.w;
  }
  __shared__ float sb[4];
  const float wsum = blockReduceSum(acc, sb);
  if(t == 0){
    const float r = Rb[row];
    Rb[row] = r / (r * wsum + SK_EPS);
  }
}

// -------------------- final: assignments + loss --------------------
__global__ __launch_bounds__(256) void final_k(const float* __restrict__ logits,
                                               const unsigned* __restrict__ shiftenc,
                                               const float* __restrict__ Cb,
                                               const float* __restrict__ Rb,
                                               float* __restrict__ out,
                                               float* __restrict__ lossacc){
  __shared__ __align__(16) float rowbuf[8192];
  __shared__ float sb[4];
  const int row = blockIdx.x, t = threadIdx.x, b = row >> 8;
  const float* lrow = logits + (size_t)row * 8192;
  float lmax = -FLT_MAX;
  #pragma unroll
  for(int it = 0; it < 8; ++it){
    const int k = it * 1024 + t * 4;
    float4 v = *(const float4*)(lrow + k);
    *(float4*)&rowbuf[k] = v;
    lmax = fmaxf(lmax, fmaxf(fmaxf(v.x, v.y), fmaxf(v.z, v.w)));
  }
  const float Lmax = blockReduceMax(lmax, sb);
  const float Rs = Rb[row];
  const unsigned* sep = shiftenc + (size_t)b * 8192;
  const float* Cp = Cb + (size_t)b * 8192;
  float pe = 0.f, sT = 0.f, sTP = 0.f;
  #pragma unroll
  for(int it = 0; it < 8; ++it){
    const int k = it * 1024 + t * 4;
    float4 v = *(const float4*)&rowbuf[k];
    float4 sh = { decf(sep[k]), decf(sep[k+1]), decf(sep[k+2]), decf(sep[k+3]) };
    float4 c4 = *(const float4*)(Cp + k);
    float ax = __expf((v.x - sh.x)*TT_INV + EXPMAX) * c4.x * Rs;
    float ay = __expf((v.y - sh.y)*TT_INV + EXPMAX) * c4.y * Rs;
    float az = __expf((v.z - sh.z)*TT_INV + EXPMAX) * c4.z * Rs;
    float aw = __expf((v.w - sh.w)*TT_INV + EXPMAX) * c4.w * Rs;
    pe += __expf((v.x - Lmax)*TP_INV) + __expf((v.y - Lmax)*TP_INV)
        + __expf((v.z - Lmax)*TP_INV) + __expf((v.w - Lmax)*TP_INV);
    sT  += (ax + ay) + (az + aw);
    sTP += (ax*v.x + ay*v.y) + (az*v.z + aw*v.w);
    float4 o = { ax, ay, az, aw };
    *(float4*)(out + (size_t)row * 8192 + k) = o;
  }
  pe  = blockReduceSum(pe, sb);
  sT  = blockReduceSum(sT, sb);
  sTP = blockReduceSum(sTP, sb);
  if(t == 0){
    const float lse = Lmax * TP_INV + __logf(pe);
    atomicAdd(lossacc, TP_INV * sTP - lse * sT);  // sum_k tgt*logp for this row
  }
}

__global__ void finscale_k(const float* __restrict__ lossacc, float* __restrict__ dst){
  dst[0] = -lossacc[0] * (1.0f / 8192.0f);
}

// ---------------------------------------------------------------------------
extern "C" void kernel_launch(void* const* d_in, const int* in_sizes, int n_in,
                              void* d_out, int out_size, void* d_ws, size_t ws_size,
                              hipStream_t stream){
  const float* x = (const float*)d_in[0];   // [32,256,1024]
  const float* W = (const float*)d_in[1];   // [8192,1024]
  float* out = (float*)d_out;               // 32*256*8192 assignments + 1 loss

  char* ws = (char*)d_ws;
  unsigned short* xb   = (unsigned short*)(ws);                 // 16 MB bf16
  unsigned short* Wb   = (unsigned short*)(ws + 16777216);      // 16 MB bf16
  float*    logits     = (float*)   (ws + 33554432);            // 256 MB f32
  unsigned* shiftenc   = (unsigned*)(ws + 301989888);           // 1 MB
  float*    tbuf       = (float*)   (ws + 303038464);           // 1 MB
  float*    Cb         = (float*)   (ws + 304087040);           // 1 MB
  float*    Rb         = (float*)   (ws + 305135616);           // 32 KB
  float*    lossacc    = (float*)   (ws + 305168384);           // 4 B

  init_k  <<<1024, 256, 0, stream>>>(shiftenc, tbuf, Cb, Rb, lossacc);
  norm_x_k<<<8192, 256, 0, stream>>>(x, xb);
  conv_w_k<<<8192, 256, 0, stream>>>(W, Wb);
  gemm_bt_k<<<dim3(64, 64), 256, 0, stream>>>(xb, Wb, logits);
  colmax_k<<<dim3(8, 32, 32), 256, 0, stream>>>(logits, shiftenc);
  for(int i = 0; i < 3; ++i){
    colsum_k<<<dim3(8, 32, 32), 256, 0, stream>>>(logits, shiftenc, Rb, tbuf);
    updC_k  <<<1024, 256, 0, stream>>>(Cb, tbuf);
    rowsum_k<<<8192, 256, 0, stream>>>(logits, shiftenc, Cb, Rb);
  }
  final_k <<<8192, 256, 0, stream>>>(logits, shiftenc, Cb, Rb, out, lossacc);
  finscale_k<<<1, 1, 0, stream>>>(lossacc, out + (size_t)(out_size - 1));
}